// Round 13
// baseline (52.767 us; speedup 1.0000x reference)
//
#include <hip/hip_runtime.h>

#define NT 8192
#define DM 4096
#define NE 8
#define NSLOT 16384
#define CAP 1024
#define PROWS 2048  // K1 blocks = partials rows

// ------------------------------------------------- fused logits + routing
// 2048 blocks x 256 threads (4 waves). Block = 4 tokens; wave w = token pair
// (w>>1) x dim-half (w&1): 8 chunks/wave. Expert loads split into two groups
// of 4 to keep live VGPR ~55; __launch_bounds__(256,8) caps VGPR at 64 so
// 8 waves/SIMD are resident (vs 4 in all prior variants) — double TLP for
// HBM latency hiding. Halves combined via LDS; wave 0 routes 4 tokens.
__global__ __launch_bounds__(256, 8) void k_logits_route(
    const float* __restrict__ x, const float* __restrict__ gw,
    float* __restrict__ topk_p, unsigned char* __restrict__ flat_e,
    float* __restrict__ partials, int* __restrict__ counter) {
  const int tid = threadIdx.x;
  const int lane = tid & 63;
  const int wv = tid >> 6;             // 0..3
  const int blk = blockIdx.x;          // 0..2047
  const int t0 = blk * 4;
  const int pair = wv >> 1;            // token pair 0/1
  const int half = wv & 1;             // dim half 0/1
  const int ta = t0 + pair * 2;
  if (blk == 0 && tid == 0) *counter = 0;  // stream-ordered vs K2

  const float4* __restrict__ xv = (const float4*)x;
  const float4* __restrict__ gv = (const float4*)gw;

  float acc[2][8];
#pragma unroll
  for (int t = 0; t < 2; ++t)
#pragma unroll
    for (int e = 0; e < 8; ++e) acc[t][e] = 0.f;

  const size_t xrowA = (size_t)ta * 1024 + half * 512;
  const size_t xrowB = xrowA + 1024;
  const int gbase = half * 512;

  for (int c = 0; c < 8; ++c) {
    const int off = c * 64 + lane;
    const float4 x0 = xv[xrowA + off];
    const float4 x1 = xv[xrowB + off];
    {
      float4 g4[4];
#pragma unroll
      for (int e = 0; e < 4; ++e) g4[e] = gv[e * 1024 + gbase + off];
#pragma unroll
      for (int e = 0; e < 4; ++e) {
        acc[0][e] = fmaf(x0.x, g4[e].x, acc[0][e]);
        acc[0][e] = fmaf(x0.y, g4[e].y, acc[0][e]);
        acc[0][e] = fmaf(x0.z, g4[e].z, acc[0][e]);
        acc[0][e] = fmaf(x0.w, g4[e].w, acc[0][e]);
        acc[1][e] = fmaf(x1.x, g4[e].x, acc[1][e]);
        acc[1][e] = fmaf(x1.y, g4[e].y, acc[1][e]);
        acc[1][e] = fmaf(x1.z, g4[e].z, acc[1][e]);
        acc[1][e] = fmaf(x1.w, g4[e].w, acc[1][e]);
      }
    }
    {
      float4 g4[4];
#pragma unroll
      for (int e = 0; e < 4; ++e) g4[e] = gv[(e + 4) * 1024 + gbase + off];
#pragma unroll
      for (int e = 0; e < 4; ++e) {
        acc[0][e + 4] = fmaf(x0.x, g4[e].x, acc[0][e + 4]);
        acc[0][e + 4] = fmaf(x0.y, g4[e].y, acc[0][e + 4]);
        acc[0][e + 4] = fmaf(x0.z, g4[e].z, acc[0][e + 4]);
        acc[0][e + 4] = fmaf(x0.w, g4[e].w, acc[0][e + 4]);
        acc[1][e + 4] = fmaf(x1.x, g4[e].x, acc[1][e + 4]);
        acc[1][e + 4] = fmaf(x1.y, g4[e].y, acc[1][e + 4]);
        acc[1][e + 4] = fmaf(x1.z, g4[e].z, acc[1][e + 4]);
        acc[1][e + 4] = fmaf(x1.w, g4[e].w, acc[1][e + 4]);
      }
    }
  }

  // wave reduce: lane t*8+e holds this half's partial logit[t][e]
  float val = 0.f;
#pragma unroll
  for (int t = 0; t < 2; ++t)
#pragma unroll
    for (int e = 0; e < 8; ++e) {
      float v = acc[t][e];
#pragma unroll
      for (int s = 32; s > 0; s >>= 1) v += __shfl_xor(v, s, 64);
      if (lane == t * 8 + e) val = v;
    }
  __shared__ float red[4][16];
  if (lane < 16) red[wv][lane] = val;
  __syncthreads();

  if (wv == 0) {
    // tot(lane s<32) = logit(token t0 + (s>>3), expert s&7)
    float tot = 0.f;
    if (lane < 32)
      tot = red[2 * (lane >> 4)][lane & 15] + red[2 * (lane >> 4) + 1][lane & 15];
    const int g = lane >> 3;  // token 0..3 (valid for lane<32)
    float l[8];
#pragma unroll
    for (int e = 0; e < 8; ++e) l[e] = __shfl(tot, g * 8 + e, 64);

    float m = l[0];
#pragma unroll
    for (int e = 1; e < 8; ++e) m = fmaxf(m, l[e]);
    float ex[8];
    float s = 0.f;
#pragma unroll
    for (int e = 0; e < 8; ++e) { ex[e] = expf(l[e] - m); s += ex[e]; }
    const float lse = m + logf(s);

    float b0 = l[0]; int i0 = 0;
#pragma unroll
    for (int e = 1; e < 8; ++e) if (l[e] > b0) { b0 = l[e]; i0 = e; }
    float b1 = -3.4e38f; int i1 = 0;
#pragma unroll
    for (int e = 0; e < 8; ++e) if (e != i0 && l[e] > b1) { b1 = l[e]; i1 = e; }

    const float t1 = expf(b1 - b0);
    const float ss = 1.f + t1;
    float p0 = 1.f / ss, p1 = t1 / ss;
    float s2 = p0 + p1;
    s2 = fmaxf(s2, 1e-8f);
    p0 /= s2; p1 /= s2;

    if (lane < 32 && (lane & 7) == 0) {
      const int tok = t0 + g;
      topk_p[2 * tok] = p0; topk_p[2 * tok + 1] = p1;
      flat_e[2 * tok] = (unsigned char)i0;
      flat_e[2 * tok + 1] = (unsigned char)i1;
    }

    // block partials: sum token-lanes {0,8,16,24}
    float vals[9];
#pragma unroll
    for (int e = 0; e < 8; ++e) vals[e] = ex[e] / s;
    vals[8] = lse * lse;
    float pout = 0.f;
#pragma unroll
    for (int mm = 0; mm < 9; ++mm) {
      const float v = vals[mm];
      const float sm = __shfl(v, 0, 64) + __shfl(v, 8, 64) +
                       __shfl(v, 16, 64) + __shfl(v, 24, 64);
      if (lane == mm) pout = sm;
    }
    if (lane < 9) partials[blk * 9 + lane] = pout;
  }
}

// ------------------------------------------- fused select + finalize + loss
// One block per expert. Compact this expert's (u, idx) into LDS; ONE
// 1024-bucket histogram on u>>20 finds the boundary bucket b* and rank R
// within it; boundary items get exact 64-bit-key (u desc, idx asc) ranking
// in LDS. Threshold key -> write outputs, usage, lb product; last block
// sums losses in fixed order (deterministic).
__global__ __launch_bounds__(256) void k_select_final(
    const float* __restrict__ flat_p, const unsigned char* __restrict__ flat_e,
    const float* __restrict__ partials, float* __restrict__ out,
    float* __restrict__ prod, float* __restrict__ zsum,
    int* __restrict__ counter) {
  const int e = blockIdx.x;
  const int t = threadIdx.x;
  const int lane = t & 63, wid = t >> 6;
  __shared__ unsigned int u_lds[NSLOT];     // 64 KB
  __shared__ unsigned short i_lds[NSLOT];   // 32 KB
  __shared__ int hist[4][1024];             // 16 KB (reused as bkeys u64[2048])
  __shared__ int wtot[4];
  __shared__ float fA[4], fZ[4];
  __shared__ int s_n, s_b, s_R2, s_cn, s_ti;
  __shared__ unsigned int s_tu;

  const uint4* __restrict__ e4p = (const uint4*)flat_e;
  const float4* __restrict__ p4p = (const float4*)flat_p;

  // ---- phase 1: count my matches
  int mycnt = 0;
#pragma unroll
  for (int it = 0; it < 4; ++it) {
    const uint4 ev = e4p[t + it * 256];
    const unsigned int w[4] = {ev.x, ev.y, ev.z, ev.w};
#pragma unroll
    for (int q = 0; q < 4; ++q)
#pragma unroll
      for (int b = 0; b < 4; ++b)
        mycnt += (((w[q] >> (8 * b)) & 0xffu) == (unsigned)e);
  }
  int pfx = mycnt;
#pragma unroll
  for (int off = 1; off < 64; off <<= 1) {
    const int tmp = __shfl_up(pfx, off, 64);
    if (lane >= off) pfx += tmp;
  }
  if (lane == 63) wtot[wid] = pfx;
  __syncthreads();
  int wbefore = 0;
  for (int w = 0; w < wid; ++w) wbefore += wtot[w];
  int pos = wbefore + pfx - mycnt;
  if (t == 255) s_n = wbefore + pfx;
  __syncthreads();
  const int n = s_n;

  // ---- phase 2: compact (always)
#pragma unroll
  for (int it = 0; it < 4; ++it) {
    const int vidx = t + it * 256;
    const uint4 ev = e4p[vidx];
    const unsigned int w[4] = {ev.x, ev.y, ev.z, ev.w};
    float4 pv[4];
#pragma unroll
    for (int q = 0; q < 4; ++q) pv[q] = p4p[vidx * 4 + q];
#pragma unroll
    for (int q = 0; q < 4; ++q) {
      const float pf[4] = {pv[q].x, pv[q].y, pv[q].z, pv[q].w};
#pragma unroll
      for (int b = 0; b < 4; ++b) {
        if (((w[q] >> (8 * b)) & 0xffu) == (unsigned)e) {
          u_lds[pos] = __float_as_uint(pf[b]);
          i_lds[pos] = (unsigned short)(vidx * 16 + q * 4 + b);
          ++pos;
        }
      }
    }
  }
  __syncthreads();

  unsigned int tu = 0u;
  int ti_ = 0x7FFFFFFF;
  if (n > CAP) {
    // ---- single histogram pass on bucket = u>>20 (monotone; u < 2^30)
    for (int i = t; i < 4096; i += 256) ((int*)hist)[i] = 0;
    __syncthreads();
    for (int i = t; i < n; i += 256)
      atomicAdd(&hist[wid][u_lds[i] >> 20], 1);
    __syncthreads();
    int c[4], chunk = 0;
#pragma unroll
    for (int k = 0; k < 4; ++k) {
      c[k] = hist[0][4 * t + k] + hist[1][4 * t + k] + hist[2][4 * t + k] +
             hist[3][4 * t + k];
      chunk += c[k];
    }
    int sfx = chunk;  // inclusive suffix scan across 256 threads
#pragma unroll
    for (int off = 1; off < 64; off <<= 1) {
      const int tmp = __shfl_down(sfx, off, 64);
      if (lane + off < 64) sfx += tmp;
    }
    if (lane == 0) wtot[wid] = sfx;
    __syncthreads();
    int wafter = 0;
    for (int w = wid + 1; w < 4; ++w) wafter += wtot[w];
    const int after = sfx + wafter - chunk;  // items in buckets > 4t+3
    if (after < CAP && after + chunk >= CAP) {  // unique crossing thread
      int sx = after, bf = -1, rf = 0;
#pragma unroll
      for (int k = 3; k >= 0; --k) {
        if (bf < 0 && sx < CAP && sx + c[k] >= CAP) { bf = 4 * t + k; rf = CAP - sx; }
        sx += c[k];
      }
      s_b = bf; s_R2 = rf;
    }
    if (t == 0) s_cn = 0;
    __syncthreads();
    const unsigned int b3 = (unsigned int)s_b;
    const int R = s_R2;  // 1-indexed rank within boundary bucket
    __syncthreads();

    // ---- collect boundary-bucket items as 64-bit keys (u desc, idx asc)
    unsigned long long* bkeys = (unsigned long long*)hist;  // 2048 slots
    for (int i = t; i < n; i += 256) {
      if ((u_lds[i] >> 20) == b3) {
        const int p = atomicAdd(&s_cn, 1);
        if (p < 2048)
          bkeys[p] = ((unsigned long long)u_lds[i] << 32) |
                     (unsigned int)(0xFFFFFFFFu - (unsigned int)i_lds[i]);
      }
    }
    __syncthreads();
    const int B = s_cn;
    if (B <= 2048) {
      for (int k = t; k < B; k += 256) {
        const unsigned long long kk = bkeys[k];
        int r = 0;
        for (int mth = 0; mth < B; ++mth) r += (bkeys[mth] > kk);
        if (r == R - 1) {
          s_tu = (unsigned int)(kk >> 32);
          s_ti = (int)(0xFFFFFFFFu - (unsigned int)kk);
        }
      }
    } else {
      // pathological fallback: exact rank without compaction
      for (int i = t; i < n; i += 256) {
        const unsigned int ui = u_lds[i];
        if ((ui >> 20) != b3) continue;
        const unsigned long long ki = ((unsigned long long)ui << 32) |
            (unsigned int)(0xFFFFFFFFu - (unsigned int)i_lds[i]);
        int r = 0;
        for (int j = 0; j < n; ++j) {
          const unsigned int uj = u_lds[j];
          if ((uj >> 20) != b3) continue;
          const unsigned long long kj = ((unsigned long long)uj << 32) |
              (unsigned int)(0xFFFFFFFFu - (unsigned int)i_lds[j]);
          r += (kj > ki);
        }
        if (r == R - 1) { s_tu = ui; s_ti = (int)i_lds[i]; }
      }
    }
    __syncthreads();
    tu = s_tu;
    ti_ = s_ti;
  }

  // ---- output phase: exactly this expert's slots (disjoint coverage)
  int myu = 0;
  for (int i = t; i < n; i += 256) {
    const unsigned int u = u_lds[i];
    const int idx = (int)i_lds[i];
    const bool kp = (u > tu) || (u == tu && idx <= ti_);
    out[idx] = kp ? (float)e : -1.0f;
    out[NSLOT + idx] = kp ? __uint_as_float(u) : 0.0f;
    myu += (kp && ((idx & 1) == 0)) ? 1 : 0;
  }
#pragma unroll
  for (int off = 32; off > 0; off >>= 1) myu += __shfl_xor(myu, off, 64);

  // ---- loss phase: ps[e] (+ z partial on block 0) over 2048 block-partials
  float a = 0.f, z = 0.f;
  for (int r = t; r < PROWS; r += 256) {
    a += partials[r * 9 + e];
    if (e == 0) z += partials[r * 9 + 8];
  }
#pragma unroll
  for (int off = 32; off > 0; off >>= 1) {
    a += __shfl_xor(a, off, 64);
    z += __shfl_xor(z, off, 64);
  }
  __syncthreads();  // before reusing wtot / writing fA,fZ
  if (lane == 0) { wtot[wid] = myu; fA[wid] = a; fZ[wid] = z; }
  __syncthreads();
  if (t == 0) {
    const int use = wtot[0] + wtot[1] + wtot[2] + wtot[3];
    const float ps_e = fA[0] + fA[1] + fA[2] + fA[3];
    out[2 * NSLOT + 2 + e] = (float)use;
    prod[e] = ps_e * (float)use;
    if (e == 0) *zsum = fZ[0] + fZ[1] + fZ[2] + fZ[3];
    __threadfence();
    const int old = atomicAdd(counter, 1);
    if (old == NE - 1) {  // last block: deterministic fixed-order sum
      __threadfence();
      float lb = 0.f;
#pragma unroll
      for (int q = 0; q < 8; ++q) lb += prod[q];
      out[2 * NSLOT]     = lb * (0.01f / (float)(NT * NE));
      out[2 * NSLOT + 1] = (*zsum / (float)NT) * 0.001f;
    }
  }
}

extern "C" void kernel_launch(void* const* d_in, const int* in_sizes, int n_in,
                              void* d_out, int out_size, void* d_ws, size_t ws_size,
                              hipStream_t stream) {
  const float* x  = (const float*)d_in[0];
  const float* gw = (const float*)d_in[1];
  float* out = (float*)d_out;
  char* ws = (char*)d_ws;

  float* topk_p         = (float*)(ws);                    // 65536 B
  unsigned char* flat_e = (unsigned char*)(ws + 65536);    // 16384 B
  float* partials       = (float*)(ws + 81920);            // 73728 B (2048*9*4)
  float* prod           = (float*)(ws + 155648);           // 32 B
  float* zsum           = (float*)(ws + 155680);           // 4 B
  int* counter          = (int*)(ws + 155712);             // 4 B

  hipLaunchKernelGGL(k_logits_route, dim3(PROWS), dim3(256), 0, stream, x, gw,
                     topk_p, flat_e, partials, counter);
  hipLaunchKernelGGL(k_select_final, dim3(8), dim3(256), 0, stream, topk_p,
                     flat_e, partials, out, prod, zsum, counter);
}

// Round 14
// 45.091 us; speedup vs baseline: 1.1702x; 1.1702x over previous
//
#include <hip/hip_runtime.h>

#define NT 8192
#define DM 4096
#define NE 8
#define NSLOT 16384
#define CAP 1024
#define PROWS 1024  // K1 blocks = partials rows

// ------------------------------------------------- fused logits + routing
// 1024 blocks x 256 threads; wave = 2 tokens x full 4096-dim row. (R12 form,
// best measured: 49.6 us total.)
__global__ __launch_bounds__(256, 4) void k_logits_route(
    const float* __restrict__ x, const float* __restrict__ gw,
    float* __restrict__ topk_p, unsigned char* __restrict__ flat_e,
    float* __restrict__ partials, int* __restrict__ counter) {
  const int tid = threadIdx.x;
  const int lane = tid & 63;
  const int wv = tid >> 6;                 // 0..3
  const int wave = blockIdx.x * 4 + wv;    // 0..4095
  const int t0 = wave * 2;
  const float4* __restrict__ xv = (const float4*)x;
  const float4* __restrict__ gv = (const float4*)gw;

  if (blockIdx.x == 0 && tid == 0) *counter = 0;  // stream-ordered vs K2

  float acc[2][8];
#pragma unroll
  for (int t = 0; t < 2; ++t)
#pragma unroll
    for (int e = 0; e < 8; ++e) acc[t][e] = 0.f;

  const size_t xrow = (size_t)t0 * 1024;
  for (int c = 0; c < 16; c += 2) {
    const int offA = c * 64 + lane;
    const int offB = offA + 64;
    const float4 xa0 = xv[xrow + offA];
    const float4 xa1 = xv[xrow + 1024 + offA];
    const float4 xb0 = xv[xrow + offB];
    const float4 xb1 = xv[xrow + 1024 + offB];

    float4 g4[8];
#pragma unroll
    for (int e = 0; e < 8; ++e) g4[e] = gv[e * 1024 + offA];
#pragma unroll
    for (int e = 0; e < 8; ++e) {
      acc[0][e] = fmaf(xa0.x, g4[e].x, acc[0][e]);
      acc[0][e] = fmaf(xa0.y, g4[e].y, acc[0][e]);
      acc[0][e] = fmaf(xa0.z, g4[e].z, acc[0][e]);
      acc[0][e] = fmaf(xa0.w, g4[e].w, acc[0][e]);
      acc[1][e] = fmaf(xa1.x, g4[e].x, acc[1][e]);
      acc[1][e] = fmaf(xa1.y, g4[e].y, acc[1][e]);
      acc[1][e] = fmaf(xa1.z, g4[e].z, acc[1][e]);
      acc[1][e] = fmaf(xa1.w, g4[e].w, acc[1][e]);
    }
#pragma unroll
    for (int e = 0; e < 8; ++e) g4[e] = gv[e * 1024 + offB];
#pragma unroll
    for (int e = 0; e < 8; ++e) {
      acc[0][e] = fmaf(xb0.x, g4[e].x, acc[0][e]);
      acc[0][e] = fmaf(xb0.y, g4[e].y, acc[0][e]);
      acc[0][e] = fmaf(xb0.z, g4[e].z, acc[0][e]);
      acc[0][e] = fmaf(xb0.w, g4[e].w, acc[0][e]);
      acc[1][e] = fmaf(xb1.x, g4[e].x, acc[1][e]);
      acc[1][e] = fmaf(xb1.y, g4[e].y, acc[1][e]);
      acc[1][e] = fmaf(xb1.z, g4[e].z, acc[1][e]);
      acc[1][e] = fmaf(xb1.w, g4[e].w, acc[1][e]);
    }
  }

  // cross-lane reduce: lane t*8+e ends up holding logit[t][e]
  float val = 0.f;
#pragma unroll
  for (int t = 0; t < 2; ++t)
#pragma unroll
    for (int e = 0; e < 8; ++e) {
      float v = acc[t][e];
#pragma unroll
      for (int s = 32; s > 0; s >>= 1) v += __shfl_xor(v, s, 64);
      if (lane == t * 8 + e) val = v;
    }

  float l[8];
#pragma unroll
  for (int e = 0; e < 8; ++e) l[e] = __shfl(val, (lane & 1) * 8 + e, 64);

  float m = l[0];
#pragma unroll
  for (int e = 1; e < 8; ++e) m = fmaxf(m, l[e]);
  float ex[8];
  float s = 0.f;
#pragma unroll
  for (int e = 0; e < 8; ++e) { ex[e] = expf(l[e] - m); s += ex[e]; }
  const float lse = m + logf(s);

  float b0 = l[0]; int i0 = 0;
#pragma unroll
  for (int e = 1; e < 8; ++e) if (l[e] > b0) { b0 = l[e]; i0 = e; }
  float b1 = -3.4e38f; int i1 = 0;
#pragma unroll
  for (int e = 0; e < 8; ++e) if (e != i0 && l[e] > b1) { b1 = l[e]; i1 = e; }

  const float t1 = expf(b1 - b0);
  const float ss = 1.f + t1;
  float p0 = 1.f / ss, p1 = t1 / ss;
  float s2 = p0 + p1;
  s2 = fmaxf(s2, 1e-8f);
  p0 /= s2; p1 /= s2;

  __shared__ float pr[8][9];
  if (lane < 2) {
    const int tok = t0 + lane;
    topk_p[2 * tok] = p0; topk_p[2 * tok + 1] = p1;
    flat_e[2 * tok] = (unsigned char)i0; flat_e[2 * tok + 1] = (unsigned char)i1;
#pragma unroll
    for (int e = 0; e < 8; ++e) pr[wv * 2 + lane][e] = ex[e] / s;
    pr[wv * 2 + lane][8] = lse * lse;
  }
  __syncthreads();
  if (tid < 9) {
    float a = 0.f;
#pragma unroll
    for (int r = 0; r < 8; ++r) a += pr[r][tid];
    partials[blockIdx.x * 9 + tid] = a;
  }
}

// ------------------------------------------- fused select + finalize + loss
// One block per expert, 1024 THREADS (16 waves): every per-thread serial
// chain (staging, compact writes, histogram, rank) is 4x shorter than the
// 256-thread version. Single-read register staging; one u>>20 histogram;
// exact 64-bit-key boundary rank; disjoint output writes; deterministic
// last-block loss reduction.
__global__ __launch_bounds__(1024) void k_select_final(
    const float* __restrict__ flat_p, const unsigned char* __restrict__ flat_e,
    const float* __restrict__ partials, float* __restrict__ out,
    float* __restrict__ prod, float* __restrict__ zsum,
    int* __restrict__ counter) {
  const int e = blockIdx.x;
  const int t = threadIdx.x;          // 0..1023
  const int lane = t & 63, wid = t >> 6;  // 16 waves
  __shared__ unsigned int u_lds[NSLOT];     // 64 KB
  __shared__ unsigned short i_lds[NSLOT];   // 32 KB
  __shared__ int hist[4][1024];             // 16 KB (reused as bkeys u64[2048])
  __shared__ int wtot[16];
  __shared__ float fA[16], fZ[16];
  __shared__ int s_n, s_b, s_R2, s_cn, s_ti;
  __shared__ unsigned int s_tu;

  const uint4* __restrict__ e4p = (const uint4*)flat_e;
  const float4* __restrict__ p4p = (const float4*)flat_p;

  // ---- single global read: thread t owns uint4 t (16 slots)
  const uint4 ev = e4p[t];
  float4 pv[4];
#pragma unroll
  for (int q = 0; q < 4; ++q) pv[q] = p4p[t * 4 + q];

  const unsigned int w[4] = {ev.x, ev.y, ev.z, ev.w};
  int mycnt = 0;
#pragma unroll
  for (int q = 0; q < 4; ++q)
#pragma unroll
    for (int b = 0; b < 4; ++b)
      mycnt += (((w[q] >> (8 * b)) & 0xffu) == (unsigned)e);

  int pfx = mycnt;
#pragma unroll
  for (int off = 1; off < 64; off <<= 1) {
    const int tmp = __shfl_up(pfx, off, 64);
    if (lane >= off) pfx += tmp;
  }
  if (lane == 63) wtot[wid] = pfx;
  __syncthreads();
  int wbefore = 0;
  for (int wq = 0; wq < wid; ++wq) wbefore += wtot[wq];
  int pos = wbefore + pfx - mycnt;
  if (t == 1023) s_n = wbefore + pfx;

  // ---- compact from registers
#pragma unroll
  for (int q = 0; q < 4; ++q) {
    const float pf[4] = {pv[q].x, pv[q].y, pv[q].z, pv[q].w};
#pragma unroll
    for (int b = 0; b < 4; ++b) {
      if (((w[q] >> (8 * b)) & 0xffu) == (unsigned)e) {
        u_lds[pos] = __float_as_uint(pf[b]);
        i_lds[pos] = (unsigned short)(t * 16 + q * 4 + b);
        ++pos;
      }
    }
  }
  __syncthreads();
  const int n = s_n;

  unsigned int tu = 0u;
  int ti_ = 0x7FFFFFFF;
  if (n > CAP) {
    // ---- single histogram pass on bucket = u>>20 (monotone; u < 2^30)
    for (int i = t; i < 4096; i += 1024) ((int*)hist)[i] = 0;
    __syncthreads();
    for (int i = t; i < n; i += 1024)
      atomicAdd(&hist[wid & 3][u_lds[i] >> 20], 1);
    __syncthreads();
    // thread t owns bucket t
    const int chunk = hist[0][t] + hist[1][t] + hist[2][t] + hist[3][t];
    int sfx = chunk;  // inclusive suffix within wave
#pragma unroll
    for (int off = 1; off < 64; off <<= 1) {
      const int tmp = __shfl_down(sfx, off, 64);
      if (lane + off < 64) sfx += tmp;
    }
    if (lane == 0) wtot[wid] = sfx;
    __syncthreads();
    int wafter = 0;
    for (int wq = wid + 1; wq < 16; ++wq) wafter += wtot[wq];
    const int after = sfx + wafter - chunk;  // items in buckets > t
    if (after < CAP && after + chunk >= CAP) {  // unique crossing thread
      s_b = t;
      s_R2 = CAP - after;
    }
    if (t == 0) s_cn = 0;
    __syncthreads();
    const unsigned int b3 = (unsigned int)s_b;
    const int R = s_R2;  // 1-indexed rank within boundary bucket
    __syncthreads();

    // ---- collect boundary-bucket items as 64-bit keys (u desc, idx asc)
    unsigned long long* bkeys = (unsigned long long*)hist;  // 2048 slots
    for (int i = t; i < n; i += 1024) {
      if ((u_lds[i] >> 20) == b3) {
        const int p = atomicAdd(&s_cn, 1);
        if (p < 2048)
          bkeys[p] = ((unsigned long long)u_lds[i] << 32) |
                     (unsigned int)(0xFFFFFFFFu - (unsigned int)i_lds[i]);
      }
    }
    __syncthreads();
    const int B = s_cn;
    if (B <= 2048) {
      for (int k = t; k < B; k += 1024) {
        const unsigned long long kk = bkeys[k];
        int r = 0;
        for (int mth = 0; mth < B; ++mth) r += (bkeys[mth] > kk);
        if (r == R - 1) {
          s_tu = (unsigned int)(kk >> 32);
          s_ti = (int)(0xFFFFFFFFu - (unsigned int)kk);
        }
      }
    } else {
      // pathological fallback: exact rank without compaction
      for (int i = t; i < n; i += 1024) {
        const unsigned int ui = u_lds[i];
        if ((ui >> 20) != b3) continue;
        const unsigned long long ki = ((unsigned long long)ui << 32) |
            (unsigned int)(0xFFFFFFFFu - (unsigned int)i_lds[i]);
        int r = 0;
        for (int j = 0; j < n; ++j) {
          const unsigned int uj = u_lds[j];
          if ((uj >> 20) != b3) continue;
          const unsigned long long kj = ((unsigned long long)uj << 32) |
              (unsigned int)(0xFFFFFFFFu - (unsigned int)i_lds[j]);
          r += (kj > ki);
        }
        if (r == R - 1) { s_tu = ui; s_ti = (int)i_lds[i]; }
      }
    }
    __syncthreads();
    tu = s_tu;
    ti_ = s_ti;
  }

  // ---- output phase: exactly this expert's slots (disjoint coverage)
  int myu = 0;
  for (int i = t; i < n; i += 1024) {
    const unsigned int u = u_lds[i];
    const int idx = (int)i_lds[i];
    const bool kp = (u > tu) || (u == tu && idx <= ti_);
    out[idx] = kp ? (float)e : -1.0f;
    out[NSLOT + idx] = kp ? __uint_as_float(u) : 0.0f;
    myu += (kp && ((idx & 1) == 0)) ? 1 : 0;
  }
#pragma unroll
  for (int off = 32; off > 0; off >>= 1) myu += __shfl_xor(myu, off, 64);

  // ---- loss phase: ps[e] (+ z partial on expert 0) over 1024 block-partials
  float a = 0.f, z = 0.f;
  for (int r = t; r < PROWS; r += 1024) {
    a += partials[r * 9 + e];
    if (e == 0) z += partials[r * 9 + 8];
  }
#pragma unroll
  for (int off = 32; off > 0; off >>= 1) {
    a += __shfl_xor(a, off, 64);
    z += __shfl_xor(z, off, 64);
  }
  __syncthreads();  // before reusing wtot / writing fA,fZ
  if (lane == 0) { wtot[wid] = myu; fA[wid] = a; fZ[wid] = z; }
  __syncthreads();
  if (t == 0) {
    int use = 0;
    float ps_e = 0.f, zz = 0.f;
#pragma unroll
    for (int wq = 0; wq < 16; ++wq) {
      use += wtot[wq];
      ps_e += fA[wq];
      zz += fZ[wq];
    }
    out[2 * NSLOT + 2 + e] = (float)use;
    prod[e] = ps_e * (float)use;
    if (e == 0) *zsum = zz;
    __threadfence();
    const int old = atomicAdd(counter, 1);
    if (old == NE - 1) {  // last block: deterministic fixed-order sum
      __threadfence();
      float lb = 0.f;
#pragma unroll
      for (int q = 0; q < 8; ++q) lb += prod[q];
      out[2 * NSLOT]     = lb * (0.01f / (float)(NT * NE));
      out[2 * NSLOT + 1] = (*zsum / (float)NT) * 0.001f;
    }
  }
}

extern "C" void kernel_launch(void* const* d_in, const int* in_sizes, int n_in,
                              void* d_out, int out_size, void* d_ws, size_t ws_size,
                              hipStream_t stream) {
  const float* x  = (const float*)d_in[0];
  const float* gw = (const float*)d_in[1];
  float* out = (float*)d_out;
  char* ws = (char*)d_ws;

  float* topk_p         = (float*)(ws);                    // 65536 B
  unsigned char* flat_e = (unsigned char*)(ws + 65536);    // 16384 B
  float* partials       = (float*)(ws + 81920);            // 36864 B
  float* prod           = (float*)(ws + 118784);           // 32 B
  float* zsum           = (float*)(ws + 118816);           // 4 B
  int* counter          = (int*)(ws + 118848);             // 4 B

  hipLaunchKernelGGL(k_logits_route, dim3(PROWS), dim3(256), 0, stream, x, gw,
                     topk_p, flat_e, partials, counter);
  hipLaunchKernelGGL(k_select_final, dim3(8), dim3(1024), 0, stream, topk_p,
                     flat_e, partials, out, prod, zsum, counter);
}